// Round 13
// baseline (239.347 us; speedup 1.0000x reference)
//
#include <hip/hip_runtime.h>

typedef __attribute__((ext_vector_type(8))) short bf16x8;
typedef __attribute__((ext_vector_type(4))) short bf16x4;
typedef __attribute__((ext_vector_type(4))) float f32x4;

__device__ __forceinline__ unsigned short f2bf(float x){
  unsigned u = __float_as_uint(x);
  u = (u + 0x7fffu + ((u >> 16) & 1u)) >> 16;
  return (unsigned short)u;
}

__device__ __forceinline__ bf16x8 cvtpack8(float4 a, float4 b){
  union { bf16x8 v; unsigned short u[8]; } p;
  p.u[0] = f2bf(a.x); p.u[1] = f2bf(a.y); p.u[2] = f2bf(a.z); p.u[3] = f2bf(a.w);
  p.u[4] = f2bf(b.x); p.u[5] = f2bf(b.y); p.u[6] = f2bf(b.z); p.u[7] = f2bf(b.w);
  return p.v;
}

// async global->LDS, 16B/lane
__device__ __forceinline__ void gload16(const void* g, void* l){
  __builtin_amdgcn_global_load_lds(
      (const __attribute__((address_space(1))) unsigned int*)g,
      (__attribute__((address_space(3))) unsigned int*)l, 16, 0, 0);
}

// ---- B tile format (bf16), element (k, c), c in [0,256): ----------------------
//   tile sg = k>>5 (16KB contiguous), chunk g = (k>>3)&3,
//   elem = sg*8192 + g*2048 + ((c + 2*g) & 255)*8 + (k&7)
// The +2g column rotation offsets each chunk's bank phase by 8 words ->
// ds_read_b128 of a fragment (4 lane-groups at 4KB offsets) is conflict-free.

// ---------------- zero init ----------------
__global__ __launch_bounds__(256) void kzero(float* __restrict__ G0, float* __restrict__ n2){
  int b = blockIdx.x;
  if (b < 256) G0[b * 256 + threadIdx.x] = 0.0f;
  else if (threadIdx.x == 0) *n2 = 0.0f;
}

// ---------------- Bjorck small kernels ----------------

__global__ __launch_bounds__(256) void knorm(const float* __restrict__ wt, float* __restrict__ n2){
  int t = blockIdx.x * 256 + threadIdx.x;
  float4 v = reinterpret_cast<const float4*>(wt)[t];
  float s = v.x*v.x + v.y*v.y + v.z*v.z + v.w*v.w;
  #pragma unroll
  for (int o = 32; o > 0; o >>= 1) s += __shfl_down(s, o, 64);
  __shared__ float red[4];
  if ((threadIdx.x & 63) == 0) red[threadIdx.x >> 6] = s;
  __syncthreads();
  if (threadIdx.x == 0) atomicAdd(n2, red[0] + red[1] + red[2] + red[3]);
}

__global__ __launch_bounds__(256) void kinit(const float* __restrict__ wt, const float* __restrict__ n2,
                                             float* __restrict__ W){
  int c = blockIdx.x;
  int r = threadIdx.x;
  float s = rsqrtf(*n2) * (1.0f / 0.3f);
  W[(size_t)r * 256 + c]         = wt[(size_t)c * 512 + r] * s;
  W[(size_t)(r + 256) * 256 + c] = wt[(size_t)c * 512 + r + 256] * s;
}

// G += partial(W^T W): grid (8 j, 8 i, 8 k-parts), 32x32 tile, k-range 64
__global__ __launch_bounds__(256) void kgram2(const float* __restrict__ W, float* __restrict__ G){
  __shared__ __align__(16) float Wi[64][32];
  __shared__ __align__(16) float Wj[64][32];
  const int t = threadIdx.x;
  const int i0 = blockIdx.y * 32, j0 = blockIdx.x * 32, k0 = blockIdx.z * 64;
  const int lr = t >> 3, lc = (t & 7) * 4;
  #pragma unroll
  for (int p = 0; p < 2; ++p){
    int r = lr + p * 32;
    *reinterpret_cast<float4*>(&Wi[r][lc]) =
        *reinterpret_cast<const float4*>(&W[(size_t)(k0 + r) * 256 + i0 + lc]);
    *reinterpret_cast<float4*>(&Wj[r][lc]) =
        *reinterpret_cast<const float4*>(&W[(size_t)(k0 + r) * 256 + j0 + lc]);
  }
  __syncthreads();
  const int tx = t & 31, iy = t >> 5;
  float g0 = 0, g1 = 0, g2 = 0, g3 = 0;
  #pragma unroll 8
  for (int k = 0; k < 64; ++k){
    float wj = Wj[k][tx];
    float4 wi = *reinterpret_cast<const float4*>(&Wi[k][iy * 4]);
    g0 = fmaf(wi.x, wj, g0); g1 = fmaf(wi.y, wj, g1);
    g2 = fmaf(wi.z, wj, g2); g3 = fmaf(wi.w, wj, g3);
  }
  float* gp = &G[(size_t)(i0 + iy * 4) * 256 + j0 + tx];
  atomicAdd(gp,       g0); atomicAdd(gp + 256, g1);
  atomicAdd(gp + 512, g2); atomicAdd(gp + 768, g3);
}

// W <- ca*W + cb*(W G) + cc*(W G) G ; 64 blocks x 512 thr, 8 rows/block.
// G tiled 64x256 through LDS: G traffic = 32MB/invocation (was 256MB).
__global__ __launch_bounds__(512) void kupdate3(float* __restrict__ W, const float* __restrict__ G,
    float* __restrict__ Gnext, float ca, float cb, float cc, int last,
    unsigned short* __restrict__ WT2){
  __shared__ __align__(16) float wl[8][256];
  __shared__ __align__(16) float Gt[64][256];
  __shared__ __align__(16) float yl[8][256];
  const int t = threadIdx.x;
  const int row = t >> 6;            // 0..7
  const int c0  = (t & 63) * 4;      // 4 consecutive cols
  const int rg  = blockIdx.x * 8 + row;

  *reinterpret_cast<float4*>(&wl[row][c0]) =
      *reinterpret_cast<const float4*>(&W[(size_t)rg * 256 + c0]);

  float y0 = 0, y1 = 0, y2 = 0, y3 = 0;
  for (int kt = 0; kt < 4; ++kt){
    __syncthreads();
    #pragma unroll
    for (int i = 0; i < 8; ++i){
      int idx = (i * 512 + t) * 4;
      int r = idx >> 8, c = idx & 255;
      *reinterpret_cast<float4*>(&Gt[r][c]) =
          *reinterpret_cast<const float4*>(&G[(size_t)(kt * 64 + r) * 256 + c]);
    }
    __syncthreads();
    #pragma unroll 4
    for (int k = 0; k < 64; ++k){
      float wv = wl[row][kt * 64 + k];
      float4 g = *reinterpret_cast<const float4*>(&Gt[k][c0]);
      y0 = fmaf(wv, g.x, y0); y1 = fmaf(wv, g.y, y1);
      y2 = fmaf(wv, g.z, y2); y3 = fmaf(wv, g.w, y3);
    }
  }
  __syncthreads();
  yl[row][c0] = y0; yl[row][c0+1] = y1; yl[row][c0+2] = y2; yl[row][c0+3] = y3;

  float d0 = 0, d1 = 0, d2 = 0, d3 = 0;
  for (int kt = 0; kt < 4; ++kt){
    __syncthreads();
    #pragma unroll
    for (int i = 0; i < 8; ++i){
      int idx = (i * 512 + t) * 4;
      int r = idx >> 8, c = idx & 255;
      *reinterpret_cast<float4*>(&Gt[r][c]) =
          *reinterpret_cast<const float4*>(&G[(size_t)(kt * 64 + r) * 256 + c]);
    }
    __syncthreads();
    #pragma unroll 4
    for (int k = 0; k < 64; ++k){
      float yv = yl[row][kt * 64 + k];
      float4 g = *reinterpret_cast<const float4*>(&Gt[k][c0]);
      d0 = fmaf(yv, g.x, d0); d1 = fmaf(yv, g.y, d1);
      d2 = fmaf(yv, g.z, d2); d3 = fmaf(yv, g.w, d3);
    }
  }

  float4 wv = *reinterpret_cast<const float4*>(&wl[row][c0]);
  float4 nw;
  nw.x = ca * wv.x + cb * y0 + cc * d0;
  nw.y = ca * wv.y + cb * y1 + cc * d1;
  nw.z = ca * wv.z + cb * y2 + cc * d2;
  nw.w = ca * wv.w + cb * y3 + cc * d3;
  *reinterpret_cast<float4*>(&W[(size_t)rg * 256 + c0]) = nw;
  if (rg < 256){
    float4 z = {0.f, 0.f, 0.f, 0.f};
    *reinterpret_cast<float4*>(&Gnext[(size_t)rg * 256 + c0]) = z;
  }
  if (last){
    int g = (rg >> 3) & 3;
    size_t base = (size_t)(rg >> 5) * 8192 + (size_t)g * 2048;
    float v[4] = {nw.x, nw.y, nw.z, nw.w};
    #pragma unroll
    for (int j = 0; j < 4; ++j)
      WT2[base + (size_t)(((c0 + j) + 2 * g) & 255) * 8 + (rg & 7)] = f2bf(v[j]);
  }
}

// ------- shared-B dbuf GEMM (small, x@W): BM=128, BK=32 ----------------------------
template<int KDIM, int KS, int EPI>
__global__ __launch_bounds__(256) void kgemmS(const float* __restrict__ A,
    const unsigned short* __restrict__ B, void* __restrict__ Cout){
  __shared__ __align__(16) unsigned short As[2][4096];
  __shared__ __align__(16) unsigned short Bs[2][8192];

  const int t = threadIdx.x;
  const int w = t >> 6, lane = t & 63;
  const int rlo = lane & 15, l16 = lane >> 4;
  const int kp = (KS > 1) ? (int)(blockIdx.x % KS) : 0;
  const int rb = (KS > 1) ? (int)(blockIdx.x / KS) : (int)blockIdx.x;
  constexpr int KLOC = KDIM / KS;
  constexpr int NS = KLOC / 32;
  const int kbase = kp * KLOC;

  const int arow = t >> 1, akh = t & 1;
  const float* astg = A + (size_t)(rb * 128 + arow) * KDIM + kbase + akh * 16;
  const int aswz = (arow >> 1) & 3;
  const int ab0 = arow * 64 + ((2 * akh)     ^ aswz) * 16;
  const int ab1 = arow * 64 + ((2 * akh + 1) ^ aswz) * 16;
  const unsigned short* bstg = B + (size_t)(kbase >> 5) * 8192 + w * 2048 + lane * 8;

  f32x4 acc[2][16];
  #pragma unroll
  for (int mf = 0; mf < 2; ++mf)
    #pragma unroll
    for (int nf = 0; nf < 16; ++nf){
      acc[mf][nf][0] = 0.f; acc[mf][nf][1] = 0.f;
      acc[mf][nf][2] = 0.f; acc[mf][nf][3] = 0.f;
    }

  float4 q0, q1, q2, q3;
#define LOADA(S) { const float* p_ = astg + (size_t)(S) * 32; \
    q0 = *reinterpret_cast<const float4*>(p_); \
    q1 = *reinterpret_cast<const float4*>(p_ + 4); \
    q2 = *reinterpret_cast<const float4*>(p_ + 8); \
    q3 = *reinterpret_cast<const float4*>(p_ + 12); }
#define WRITEA(BUF) { char* b_ = reinterpret_cast<char*>(&As[BUF][0]); \
    *reinterpret_cast<bf16x8*>(b_ + ab0) = cvtpack8(q0, q1); \
    *reinterpret_cast<bf16x8*>(b_ + ab1) = cvtpack8(q2, q3); }
#define STAGE_B(BUF, S) { \
    _Pragma("unroll") \
    for (int i = 0; i < 4; ++i) \
      gload16(bstg + (size_t)(S) * 8192 + i * 512, &Bs[BUF][w * 2048 + i * 512]); }
#define COMPUTE(BUF) { \
    bf16x8 afr[2]; \
    const char* ab_ = reinterpret_cast<const char*>(&As[BUF][0]); \
    _Pragma("unroll") \
    for (int mf = 0; mf < 2; ++mf){ \
      int row = w * 32 + mf * 16 + rlo; \
      afr[mf] = *reinterpret_cast<const bf16x8*>( \
          ab_ + row * 64 + ((l16 ^ ((row >> 1) & 3)) * 16)); \
    } \
    _Pragma("unroll") \
    for (int nf = 0; nf < 16; ++nf){ \
      bf16x8 bf_ = *reinterpret_cast<const bf16x8*>( \
          &Bs[BUF][l16 * 2048 + (((nf * 16 + rlo) + 2 * l16) & 255) * 8]); \
      acc[0][nf] = __builtin_amdgcn_mfma_f32_16x16x32_bf16(afr[0], bf_, acc[0][nf], 0, 0, 0); \
      acc[1][nf] = __builtin_amdgcn_mfma_f32_16x16x32_bf16(afr[1], bf_, acc[1][nf], 0, 0, 0); \
    } }

  STAGE_B(0, 0);
  LOADA(0);
  WRITEA(0);
  __syncthreads();

  #pragma unroll 1
  for (int s = 0; s < NS; ++s){
    const int cur = s & 1;
    if (s + 1 < NS){ STAGE_B(cur ^ 1, s + 1); LOADA(s + 1); }
    COMPUTE(cur);
    if (s + 1 < NS) WRITEA(cur ^ 1);
    __syncthreads();
  }
#undef LOADA
#undef WRITEA
#undef STAGE_B
#undef COMPUTE

  if constexpr (EPI == 0){
    unsigned short* H = reinterpret_cast<unsigned short*>(Cout);
    #pragma unroll
    for (int mf = 0; mf < 2; ++mf)
      #pragma unroll
      for (int nf = 0; nf < 16; ++nf){
        int c  = nf * 16 + rlo;
        int m0 = rb * 128 + w * 32 + mf * 16 + (l16 << 2);
        int g  = (m0 >> 3) & 3;
        size_t e = (size_t)(m0 >> 5) * 8192 + (size_t)g * 2048
                 + (size_t)((c + 2 * g) & 255) * 8 + (m0 & 7);
        union { bf16x4 v; unsigned short u[4]; } p;
        p.u[0] = f2bf(acc[mf][nf][0]);
        p.u[1] = f2bf(acc[mf][nf][1]);
        p.u[2] = f2bf(acc[mf][nf][2]);
        p.u[3] = f2bf(acc[mf][nf][3]);
        *reinterpret_cast<bf16x4*>(&H[e]) = p.v;
      }
  } else {
    float* O = reinterpret_cast<float*>(Cout) + (size_t)kp * 8192 * 256;
    #pragma unroll
    for (int mf = 0; mf < 2; ++mf)
      #pragma unroll
      for (int nf = 0; nf < 16; ++nf){
        int c  = nf * 16 + rlo;
        int m0 = rb * 128 + w * 32 + mf * 16 + (l16 << 2);
        #pragma unroll
        for (int j = 0; j < 4; ++j)
          O[(size_t)(m0 + j) * 256 + c] = acc[mf][nf][j];
      }
  }
}

// ------- BIG GEMM: counted-vmcnt depth-2 pipeline, KS=8 (32 rb x 8 kp = 256) -------
// BM=256 (8 waves x 32 rows x 256 cols), BK=32, 1 block/CU.
// Per step per wave: 4 A-loads (global->reg, MFMA layout, depth-2), 2 B-DMA
// (global->LDS, triple-buffered, depth-2), vmcnt(6)+barrier (never 0 mid-loop).
template<int KDIM, int KS>
__global__ __launch_bounds__(512, 1) void kgemmF2(const float* __restrict__ A,
    const unsigned short* __restrict__ B, float* __restrict__ Cout){
  __shared__ __align__(16) unsigned short Bs[3][8192];

  const int t = threadIdx.x;
  const int w = t >> 6, lane = t & 63;
  const int rlo = lane & 15, l16 = lane >> 4;
  const int kp = (int)(blockIdx.x % KS);
  const int rb = (int)(blockIdx.x / KS);
  constexpr int KLOC = KDIM / KS;
  constexpr int NS = KLOC / 32;
  const int kbase = kp * KLOC;

  const int row0 = rb * 256 + w * 32 + rlo;
  const float* a0 = A + (size_t)row0 * KDIM + kbase + l16 * 8;
  const float* a1 = a0 + (size_t)16 * KDIM;
  const unsigned short* bstg = B + (size_t)(kbase >> 5) * 8192 + w * 1024 + lane * 8;

  f32x4 acc[2][16];
  #pragma unroll
  for (int mf = 0; mf < 2; ++mf)
    #pragma unroll
    for (int nf = 0; nf < 16; ++nf){
      acc[mf][nf][0] = 0.f; acc[mf][nf][1] = 0.f;
      acc[mf][nf][2] = 0.f; acc[mf][nf][3] = 0.f;
    }

#define LDA(Q, S) { const float* pa_ = a0 + (size_t)(S) * 32; \
    const float* pb_ = a1 + (size_t)(S) * 32; \
    Q[0] = *reinterpret_cast<const float4*>(pa_); \
    Q[1] = *reinterpret_cast<const float4*>(pa_ + 4); \
    Q[2] = *reinterpret_cast<const float4*>(pb_); \
    Q[3] = *reinterpret_cast<const float4*>(pb_ + 4); }
#define STB(BUF, S) { \
    _Pragma("unroll") \
    for (int i = 0; i < 2; ++i) \
      gload16(bstg + (size_t)(S) * 8192 + i * 512, &Bs[BUF][w * 1024 + i * 512]); }
#define STEP(PB, Q, S) { \
    bf16x8 afr0 = cvtpack8(Q[0], Q[1]); \
    bf16x8 afr1 = cvtpack8(Q[2], Q[3]); \
    { int st_ = ((S) + 2 < NS) ? (S) + 2 : NS - 1; \
      int pn_ = (PB) + 2; if (pn_ >= 3) pn_ -= 3; \
      LDA(Q, st_); \
      STB(pn_, st_); } \
    _Pragma("unroll") \
    for (int nf = 0; nf < 16; nf += 2){ \
      bf16x8 b0 = *reinterpret_cast<const bf16x8*>( \
          &Bs[PB][l16 * 2048 + (((nf * 16 + rlo) + 2 * l16) & 255) * 8]); \
      bf16x8 b1 = *reinterpret_cast<const bf16x8*>( \
          &Bs[PB][l16 * 2048 + ((((nf + 1) * 16 + rlo) + 2 * l16) & 255) * 8]); \
      acc[0][nf]   = __builtin_amdgcn_mfma_f32_16x16x32_bf16(afr0, b0, acc[0][nf], 0, 0, 0); \
      acc[1][nf]   = __builtin_amdgcn_mfma_f32_16x16x32_bf16(afr1, b0, acc[1][nf], 0, 0, 0); \
      acc[0][nf+1] = __builtin_amdgcn_mfma_f32_16x16x32_bf16(afr0, b1, acc[0][nf+1], 0, 0, 0); \
      acc[1][nf+1] = __builtin_amdgcn_mfma_f32_16x16x32_bf16(afr1, b1, acc[1][nf+1], 0, 0, 0); \
    } \
    asm volatile("s_waitcnt vmcnt(6)" ::: "memory"); \
    __builtin_amdgcn_s_barrier(); \
    asm volatile("" ::: "memory"); }

  float4 q0[4], q1[4];
  STB(0, 0);
  STB(1, 1);
  LDA(q0, 0);
  LDA(q1, 1);
  asm volatile("s_waitcnt vmcnt(4)" ::: "memory");
  __builtin_amdgcn_s_barrier();
  asm volatile("" ::: "memory");

  int p = 0;
  #pragma unroll 1
  for (int s = 0; s < NS; s += 2){
    int p1 = p + 1; if (p1 >= 3) p1 -= 3;
    STEP(p, q0, s);
    STEP(p1, q1, s + 1);
    p = p1 + 1; if (p >= 3) p -= 3;
  }
#undef LDA
#undef STB
#undef STEP

  float* O = Cout + (size_t)kp * 8192 * 256;
  #pragma unroll
  for (int mf = 0; mf < 2; ++mf)
    #pragma unroll
    for (int nf = 0; nf < 16; ++nf){
      int c  = nf * 16 + rlo;
      int m0 = rb * 256 + w * 32 + mf * 16 + (l16 << 2);
      #pragma unroll
      for (int j = 0; j < 4; ++j)
        O[(size_t)(m0 + j) * 256 + c] = acc[mf][nf][j];
    }
}

// out = relu(sum of 8 partials)
__global__ __launch_bounds__(256) void kreduce8(const float* __restrict__ P, float* __restrict__ O){
  size_t i = (size_t)blockIdx.x * 256 + threadIdx.x;
  const float4* p = reinterpret_cast<const float4*>(P);
  float4 r = p[i];
  #pragma unroll
  for (int q = 1; q < 8; ++q){
    float4 b = p[i + (size_t)q * 524288];
    r.x += b.x; r.y += b.y; r.z += b.z; r.w += b.w;
  }
  r.x = fmaxf(r.x, 0.f); r.y = fmaxf(r.y, 0.f);
  r.z = fmaxf(r.z, 0.f); r.w = fmaxf(r.w, 0.f);
  reinterpret_cast<float4*>(O)[i] = r;
}

// ---------------- launcher ----------------

extern "C" void kernel_launch(void* const* d_in, const int* in_sizes, int n_in,
                              void* d_out, int out_size, void* d_ws, size_t ws_size,
                              hipStream_t stream) {
  const float* x   = (const float*)d_in[0];   // [8192,512]
  const float* adj = (const float*)d_in[1];   // [8192,8192]
  const float* wt  = (const float*)d_in[2];   // [256,512]
  float* out = (float*)d_out;                 // [8192,256]

  char* ws = (char*)d_ws;
  float* n2            = (float*)ws;                                    // 4 B
  float* W             = (float*)(ws + 4096);                           // 512 KB
  float* G0            = (float*)(ws + 4096 + 524288);                  // 256 KB
  float* G1            = (float*)(ws + 4096 + 524288 + 262144);         // 256 KB
  unsigned short* WT2  = (unsigned short*)(ws + 4096 + 524288 + 2*262144);   // 256 KB
  unsigned short* HT2  = (unsigned short*)(ws + 4096 + 524288 + 3*262144);   // 4 MB
  float* Cpart         = (float*)(ws + 4096 + 524288 + 3*262144 + 4194304);  // 64 MB

  kzero<<<257, 256, 0, stream>>>(G0, n2);
  knorm<<<128, 256, 0, stream>>>(wt, n2);
  kinit<<<256, 256, 0, stream>>>(wt, n2, W);

  // 4 iterations: aggressive quintic, Muon quintic, 2 exact Bjorck steps
  const float ca[4] = { 4.2000f, 3.4445f, 1.875f, 1.875f };
  const float cb[4] = {-9.0000f, -4.7750f, -1.25f, -1.25f };
  const float cc[4] = {-6.8000f, 2.0315f, 0.375f, 0.375f };
  float* Gb[2] = {G0, G1};
  for (int it = 0; it < 4; ++it){
    float* Gc = Gb[it & 1];
    float* Gn = Gb[(it + 1) & 1];
    kgram2<<<dim3(8, 8, 8), 256, 0, stream>>>(W, Gc);
    kupdate3<<<64, 512, 0, stream>>>(W, Gc, Gn, ca[it], cb[it], cc[it], it == 3 ? 1 : 0, WT2);
  }

  // h (rotated B tile format, bf16) = x @ W
  kgemmS<512, 1, 0><<<64, 256, 0, stream>>>(x, WT2, (void*)HT2);
  // partials: Cpart[kp] = adj[:, kslice] @ h[kslice, :]  (32 rb x 8 kp = 1 block/CU)
  kgemmF2<8192, 8><<<256, 512, 0, stream>>>(adj, HT2, Cpart);
  // out = relu(sum partials)
  kreduce8<<<2048, 256, 0, stream>>>(Cpart, out);
}